// Round 1
// baseline (717.635 us; speedup 1.0000x reference)
//
#include <hip/hip_runtime.h>

// GeomGCN single-channel: t = (feature @ W^T) * norm  -> gather(src,div) ->
// scatter-add to (dst,div) -> *norm -> relu.
// Constants from reference: N=100000, E=1600000, IN=128, OUT=64, D=4 (D*OUT=256).

#define IN_F   128
#define OUTC   256   // D * OUT

// ---------------------------------------------------------------------------
// Kernel 1: t[n][c] = (sum_k feature[n][k] * W[c][k]) * norm[n]
// W is [D,OUT,IN] contiguous == [256][128] row-major with row c = d*64+o.
// Tiled fp32 GEMM: 128x128 block tile, 256 threads, 8x8 microtile.
// ---------------------------------------------------------------------------
__global__ __launch_bounds__(256) void gemm_norm_kernel(
    const float* __restrict__ feat, const float* __restrict__ W,
    const float* __restrict__ norm, float* __restrict__ t, int nNodes)
{
    __shared__ float As[128][132];   // transposed: As[k][m]
    __shared__ float Bs[128][132];   // transposed: Bs[k][n]

    const int tid = threadIdx.x;
    const int m0 = blockIdx.x * 128;
    const int n0 = blockIdx.y * 128;

    // Cooperative load: 128x128 floats each for A and B, transposed into LDS.
    #pragma unroll
    for (int iter = 0; iter < 16; ++iter) {
        const int idx = iter * 1024 + tid * 4;   // 0..16383, step 4
        const int row = idx >> 7;                // 0..127
        const int col = idx & 127;               // multiple of 4
        float4 v = make_float4(0.f, 0.f, 0.f, 0.f);
        const int g = m0 + row;
        if (g < nNodes) v = *(const float4*)(feat + (size_t)g * IN_F + col);
        As[col + 0][row] = v.x; As[col + 1][row] = v.y;
        As[col + 2][row] = v.z; As[col + 3][row] = v.w;
        const float4 w = *(const float4*)(W + (size_t)(n0 + row) * IN_F + col);
        Bs[col + 0][row] = w.x; Bs[col + 1][row] = w.y;
        Bs[col + 2][row] = w.z; Bs[col + 3][row] = w.w;
    }
    __syncthreads();

    const int tx = tid & 15, ty = tid >> 4;
    const int mb = ty * 8, nb = tx * 8;
    float acc[8][8] = {};

    #pragma unroll 2
    for (int k = 0; k < 128; ++k) {
        const float4 a0 = *(const float4*)&As[k][mb];
        const float4 a1 = *(const float4*)&As[k][mb + 4];
        const float4 b0 = *(const float4*)&Bs[k][nb];
        const float4 b1 = *(const float4*)&Bs[k][nb + 4];
        const float a[8] = {a0.x, a0.y, a0.z, a0.w, a1.x, a1.y, a1.z, a1.w};
        const float b[8] = {b0.x, b0.y, b0.z, b0.w, b1.x, b1.y, b1.z, b1.w};
        #pragma unroll
        for (int i = 0; i < 8; ++i)
            #pragma unroll
            for (int j = 0; j < 8; ++j)
                acc[i][j] = fmaf(a[i], b[j], acc[i][j]);
    }

    #pragma unroll
    for (int i = 0; i < 8; ++i) {
        const int gm = m0 + mb + i;
        if (gm >= nNodes) continue;
        const float nm = norm[gm];
        float4 o0, o1;
        o0.x = acc[i][0] * nm; o0.y = acc[i][1] * nm;
        o0.z = acc[i][2] * nm; o0.w = acc[i][3] * nm;
        o1.x = acc[i][4] * nm; o1.y = acc[i][5] * nm;
        o1.z = acc[i][6] * nm; o1.w = acc[i][7] * nm;
        float* p = t + (size_t)gm * OUTC + n0 + nb;
        *(float4*)(p + 0) = o0;
        *(float4*)(p + 4) = o1;
    }
}

// ---------------------------------------------------------------------------
// Kernel 2: one wave per edge. lane l handles output feature l (0..63).
//   out[dst*256 + div*64 + l] += t[src*256 + div*64 + l]
// ---------------------------------------------------------------------------
__global__ __launch_bounds__(256) void scatter_kernel(
    const float* __restrict__ t, const int* __restrict__ src,
    const int* __restrict__ dst, const int* __restrict__ ediv,
    float* __restrict__ out, int nEdges)
{
    const int wave = (int)((blockIdx.x * (unsigned)blockDim.x + threadIdx.x) >> 6);
    const int lane = threadIdx.x & 63;
    if (wave >= nEdges) return;
    const int s  = src[wave];
    const int d  = dst[wave];
    const int dv = ediv[wave];
    const int c  = dv * 64 + lane;
    const float v = t[(size_t)s * OUTC + c];
    atomicAdd(out + (size_t)d * OUTC + c, v);
}

// ---------------------------------------------------------------------------
// Kernel 3: out[n][c] = relu(out[n][c] * norm[n]), vectorized float4.
// ---------------------------------------------------------------------------
__global__ __launch_bounds__(256) void finalize_kernel(
    float* __restrict__ out, const float* __restrict__ norm, int nNodes)
{
    const int i = blockIdx.x * blockDim.x + threadIdx.x;  // float4 index
    const int total = nNodes * (OUTC / 4);
    if (i >= total) return;
    const int node = i >> 6;   // 64 float4 per node
    const float nm = norm[node];
    float4 v = ((const float4*)out)[i];
    v.x = fmaxf(v.x * nm, 0.f);
    v.y = fmaxf(v.y * nm, 0.f);
    v.z = fmaxf(v.z * nm, 0.f);
    v.w = fmaxf(v.w * nm, 0.f);
    ((float4*)out)[i] = v;
}

extern "C" void kernel_launch(void* const* d_in, const int* in_sizes, int n_in,
                              void* d_out, int out_size, void* d_ws, size_t ws_size,
                              hipStream_t stream) {
    const float* feat = (const float*)d_in[0];   // [N,128]
    const float* W    = (const float*)d_in[1];   // [4,64,128] == [256][128]
    const float* norm = (const float*)d_in[2];   // [N,1]
    const int*   src  = (const int*)d_in[3];     // [E]
    const int*   dst  = (const int*)d_in[4];     // [E]
    const int*   ediv = (const int*)d_in[5];     // [E]
    float* out = (float*)d_out;                  // [N,256]
    float* t   = (float*)d_ws;                   // [N,256] scratch (102.4 MB)

    const int nNodes = in_sizes[0] / IN_F;
    const int nEdges = in_sizes[3];

    // out accumulates the segment sum -> must start at zero every launch.
    hipMemsetAsync(out, 0, (size_t)nNodes * OUTC * sizeof(float), stream);

    dim3 g1((nNodes + 127) / 128, 2);
    gemm_norm_kernel<<<g1, 256, 0, stream>>>(feat, W, norm, t, nNodes);

    // 4 waves (edges) per 256-thread block.
    const int sblocks = (nEdges + 3) / 4;
    scatter_kernel<<<sblocks, 256, 0, stream>>>(t, src, dst, ediv, out, nEdges);

    const int total4 = nNodes * (OUTC / 4);
    finalize_kernel<<<(total4 + 255) / 256, 256, 0, stream>>>(out, norm, nNodes);
}

// Round 2
// 695.867 us; speedup vs baseline: 1.0313x; 1.0313x over previous
//
#include <hip/hip_runtime.h>

// GeomGCN single-channel, restructured:
//   1. Wt[k][c] = W[c][k]                       (transpose, 128x256)
//   2. t[n][c] = (feat[n,:]·Wt[:,c]) * norm[n]  (GEMM, LDS-A / streamed-B)
//   3. counting-sort edges by dst (histogram -> 1-block scan -> placement)
//   4. per-node wave aggregation (no atomics) + fused *norm + relu
// Constants: N=100000, E=1600000, IN=128, OUT=64, D=4 (D*OUT=256).

#define IN_F   128
#define OUTC   256
#define GM_ROWS 64

// ---------------------------------------------------------------------------
// Wt[k*256 + c] = W[c*128 + k]
// ---------------------------------------------------------------------------
__global__ __launch_bounds__(256) void transposeW_kernel(
    const float* __restrict__ W, float* __restrict__ Wt)
{
    const int idx = blockIdx.x * 256 + threadIdx.x;   // 0..32767
    const int c = idx >> 7;
    const int k = idx & 127;
    Wt[k * OUTC + c] = W[idx];
}

// ---------------------------------------------------------------------------
// GEMM: tile M=64 x N=256(all) x K=128(all). 256 threads, 8x8 microtile.
// A staged (transposed) in LDS (35 KB -> ~4 blocks/CU); B streamed from Wt
// (128 KB, L1/L2 resident).
// ---------------------------------------------------------------------------
__global__ __launch_bounds__(256) void gemm_kernel(
    const float* __restrict__ feat, const float* __restrict__ Wt,
    const float* __restrict__ norm, float* __restrict__ t, int nNodes)
{
    __shared__ float As[128][GM_ROWS + 4];   // [k][m], 128x68 floats = 34.8 KB

    const int tid = threadIdx.x;
    const int m0 = blockIdx.x * GM_ROWS;

    // Load 64 rows x 128 k, transposed into LDS. 8192 floats = 8 float4/thread.
    #pragma unroll
    for (int it = 0; it < 8; ++it) {
        const int idx = it * 1024 + tid * 4;
        const int row = idx >> 7;      // 0..63
        const int col = idx & 127;     // k, multiple of 4
        float4 v = make_float4(0.f, 0.f, 0.f, 0.f);
        const int g = m0 + row;
        if (g < nNodes) v = *(const float4*)(feat + (size_t)g * IN_F + col);
        As[col + 0][row] = v.x; As[col + 1][row] = v.y;
        As[col + 2][row] = v.z; As[col + 3][row] = v.w;
    }
    __syncthreads();

    const int tx = tid & 31;          // col-group: 32 x 8 = 256 cols
    const int ty = tid >> 5;          // row-group: 8 x 8 = 64 rows
    const int mb = ty * 8, nb = tx * 8;
    float acc[8][8] = {};

    #pragma unroll 4
    for (int k = 0; k < 128; ++k) {
        const float4 a0 = *(const float4*)&As[k][mb];
        const float4 a1 = *(const float4*)&As[k][mb + 4];
        const float4 b0 = *(const float4*)(Wt + k * OUTC + nb);
        const float4 b1 = *(const float4*)(Wt + k * OUTC + nb + 4);
        const float a[8] = {a0.x, a0.y, a0.z, a0.w, a1.x, a1.y, a1.z, a1.w};
        const float b[8] = {b0.x, b0.y, b0.z, b0.w, b1.x, b1.y, b1.z, b1.w};
        #pragma unroll
        for (int i = 0; i < 8; ++i)
            #pragma unroll
            for (int j = 0; j < 8; ++j)
                acc[i][j] = fmaf(a[i], b[j], acc[i][j]);
    }

    #pragma unroll
    for (int i = 0; i < 8; ++i) {
        const int gm = m0 + mb + i;
        if (gm >= nNodes) continue;
        const float nm = norm[gm];
        float4 o0, o1;
        o0.x = acc[i][0] * nm; o0.y = acc[i][1] * nm;
        o0.z = acc[i][2] * nm; o0.w = acc[i][3] * nm;
        o1.x = acc[i][4] * nm; o1.y = acc[i][5] * nm;
        o1.z = acc[i][6] * nm; o1.w = acc[i][7] * nm;
        float* p = t + (size_t)gm * OUTC + nb;
        *(float4*)(p + 0) = o0;
        *(float4*)(p + 4) = o1;
    }
}

// ---------------------------------------------------------------------------
// Histogram: cursor[d] += 1 for each edge destination d.
// ---------------------------------------------------------------------------
__global__ __launch_bounds__(256) void histogram_kernel(
    const int* __restrict__ dst, int* __restrict__ cursor, int nEdges)
{
    const int e = blockIdx.x * 256 + threadIdx.x;
    if (e >= nEdges) return;
    atomicAdd(&cursor[dst[e]], 1);
}

// ---------------------------------------------------------------------------
// In-place exclusive scan of cursor[0..n) — single block of 256 threads.
// After this, cursor[i] = sum of degrees of nodes < i.
// ---------------------------------------------------------------------------
__global__ __launch_bounds__(256) void scan_kernel(int* __restrict__ c, int n)
{
    __shared__ int psum[256];
    const int tid = threadIdx.x;
    const int chunk = (n + 255) / 256;
    const int lo = tid * chunk;
    const int hi = min(lo + chunk, n);
    int s = 0;
    for (int i = lo; i < hi; ++i) s += c[i];
    psum[tid] = s;
    __syncthreads();
    if (tid == 0) {
        int run = 0;
        for (int i = 0; i < 256; ++i) { const int v = psum[i]; psum[i] = run; run += v; }
    }
    __syncthreads();
    int run = psum[tid];
    for (int i = lo; i < hi; ++i) { const int v = c[i]; c[i] = run; run += v; }
}

// ---------------------------------------------------------------------------
// Placement: pos = cursor[dst]++; payload[pos] = (src<<2)|div.
// After this, cursor[n] == end offset of node n's range (== old cursor[n+1]).
// ---------------------------------------------------------------------------
__global__ __launch_bounds__(256) void place_kernel(
    const int* __restrict__ src, const int* __restrict__ dst,
    const int* __restrict__ ediv, int* __restrict__ cursor,
    int* __restrict__ payload, int nEdges)
{
    const int e = blockIdx.x * 256 + threadIdx.x;
    if (e >= nEdges) return;
    const int d = dst[e];
    const int pos = atomicAdd(&cursor[d], 1);
    payload[pos] = (src[e] << 2) | ediv[e];
}

// ---------------------------------------------------------------------------
// Aggregation: one wave per node; lane = output feature (0..63), acc per div.
// out[n][dv*64+lane] = relu(norm[n] * sum_{edges->(n,dv)} t[src][dv*64+lane])
// ---------------------------------------------------------------------------
__global__ __launch_bounds__(256) void aggregate_kernel(
    const float* __restrict__ t, const int* __restrict__ cursor,
    const int* __restrict__ payload, const float* __restrict__ norm,
    float* __restrict__ out, int nNodes)
{
    const int wave = (int)((blockIdx.x * 256u + threadIdx.x) >> 6);
    const int lane = threadIdx.x & 63;
    if (wave >= nNodes) return;
    const int e0 = (wave == 0) ? 0 : cursor[wave - 1];
    const int e1 = cursor[wave];

    float acc0 = 0.f, acc1 = 0.f, acc2 = 0.f, acc3 = 0.f;
    int e = e0;
    for (; e + 1 < e1; e += 2) {
        const int p0 = payload[e];
        const int p1 = payload[e + 1];
        const float v0 = t[(size_t)(p0 >> 2) * OUTC + (p0 & 3) * 64 + lane];
        const float v1 = t[(size_t)(p1 >> 2) * OUTC + (p1 & 3) * 64 + lane];
        const int d0 = p0 & 3, d1 = p1 & 3;
        acc0 += (d0 == 0 ? v0 : 0.f) + (d1 == 0 ? v1 : 0.f);
        acc1 += (d0 == 1 ? v0 : 0.f) + (d1 == 1 ? v1 : 0.f);
        acc2 += (d0 == 2 ? v0 : 0.f) + (d1 == 2 ? v1 : 0.f);
        acc3 += (d0 == 3 ? v0 : 0.f) + (d1 == 3 ? v1 : 0.f);
    }
    if (e < e1) {
        const int p0 = payload[e];
        const float v0 = t[(size_t)(p0 >> 2) * OUTC + (p0 & 3) * 64 + lane];
        const int d0 = p0 & 3;
        acc0 += (d0 == 0 ? v0 : 0.f);
        acc1 += (d0 == 1 ? v0 : 0.f);
        acc2 += (d0 == 2 ? v0 : 0.f);
        acc3 += (d0 == 3 ? v0 : 0.f);
    }

    const float nm = norm[wave];
    float* po = out + (size_t)wave * OUTC;
    po[0 * 64 + lane] = fmaxf(acc0 * nm, 0.f);
    po[1 * 64 + lane] = fmaxf(acc1 * nm, 0.f);
    po[2 * 64 + lane] = fmaxf(acc2 * nm, 0.f);
    po[3 * 64 + lane] = fmaxf(acc3 * nm, 0.f);
}

// ===========================================================================
// Fallback path (round-1 pipeline) in case ws_size < required.
// ===========================================================================
__global__ __launch_bounds__(256) void gemm_norm_kernel_fb(
    const float* __restrict__ feat, const float* __restrict__ W,
    const float* __restrict__ norm, float* __restrict__ t, int nNodes)
{
    __shared__ float As[128][132];
    __shared__ float Bs[128][132];
    const int tid = threadIdx.x;
    const int m0 = blockIdx.x * 128;
    const int n0 = blockIdx.y * 128;
    #pragma unroll
    for (int iter = 0; iter < 16; ++iter) {
        const int idx = iter * 1024 + tid * 4;
        const int row = idx >> 7;
        const int col = idx & 127;
        float4 v = make_float4(0.f, 0.f, 0.f, 0.f);
        const int g = m0 + row;
        if (g < nNodes) v = *(const float4*)(feat + (size_t)g * IN_F + col);
        As[col + 0][row] = v.x; As[col + 1][row] = v.y;
        As[col + 2][row] = v.z; As[col + 3][row] = v.w;
        const float4 w = *(const float4*)(W + (size_t)(n0 + row) * IN_F + col);
        Bs[col + 0][row] = w.x; Bs[col + 1][row] = w.y;
        Bs[col + 2][row] = w.z; Bs[col + 3][row] = w.w;
    }
    __syncthreads();
    const int tx = tid & 15, ty = tid >> 4;
    const int mb = ty * 8, nb = tx * 8;
    float acc[8][8] = {};
    #pragma unroll 2
    for (int k = 0; k < 128; ++k) {
        const float4 a0 = *(const float4*)&As[k][mb];
        const float4 a1 = *(const float4*)&As[k][mb + 4];
        const float4 b0 = *(const float4*)&Bs[k][nb];
        const float4 b1 = *(const float4*)&Bs[k][nb + 4];
        const float a[8] = {a0.x, a0.y, a0.z, a0.w, a1.x, a1.y, a1.z, a1.w};
        const float b[8] = {b0.x, b0.y, b0.z, b0.w, b1.x, b1.y, b1.z, b1.w};
        #pragma unroll
        for (int i = 0; i < 8; ++i)
            #pragma unroll
            for (int j = 0; j < 8; ++j)
                acc[i][j] = fmaf(a[i], b[j], acc[i][j]);
    }
    #pragma unroll
    for (int i = 0; i < 8; ++i) {
        const int gm = m0 + mb + i;
        if (gm >= nNodes) continue;
        const float nm = norm[gm];
        float4 o0, o1;
        o0.x = acc[i][0] * nm; o0.y = acc[i][1] * nm;
        o0.z = acc[i][2] * nm; o0.w = acc[i][3] * nm;
        o1.x = acc[i][4] * nm; o1.y = acc[i][5] * nm;
        o1.z = acc[i][6] * nm; o1.w = acc[i][7] * nm;
        float* p = t + (size_t)gm * OUTC + n0 + nb;
        *(float4*)(p + 0) = o0;
        *(float4*)(p + 4) = o1;
    }
}

__global__ __launch_bounds__(256) void scatter_kernel_fb(
    const float* __restrict__ t, const int* __restrict__ src,
    const int* __restrict__ dst, const int* __restrict__ ediv,
    float* __restrict__ out, int nEdges)
{
    const int wave = (int)((blockIdx.x * 256u + threadIdx.x) >> 6);
    const int lane = threadIdx.x & 63;
    if (wave >= nEdges) return;
    const int c = ediv[wave] * 64 + lane;
    atomicAdd(out + (size_t)dst[wave] * OUTC + c, t[(size_t)src[wave] * OUTC + c]);
}

__global__ __launch_bounds__(256) void finalize_kernel_fb(
    float* __restrict__ out, const float* __restrict__ norm, int nNodes)
{
    const int i = blockIdx.x * 256 + threadIdx.x;
    if (i >= nNodes * (OUTC / 4)) return;
    const float nm = norm[i >> 6];
    float4 v = ((const float4*)out)[i];
    v.x = fmaxf(v.x * nm, 0.f);
    v.y = fmaxf(v.y * nm, 0.f);
    v.z = fmaxf(v.z * nm, 0.f);
    v.w = fmaxf(v.w * nm, 0.f);
    ((float4*)out)[i] = v;
}

// ===========================================================================
extern "C" void kernel_launch(void* const* d_in, const int* in_sizes, int n_in,
                              void* d_out, int out_size, void* d_ws, size_t ws_size,
                              hipStream_t stream) {
    const float* feat = (const float*)d_in[0];   // [N,128]
    const float* W    = (const float*)d_in[1];   // [4,64,128] == [256][128]
    const float* norm = (const float*)d_in[2];   // [N,1]
    const int*   src  = (const int*)d_in[3];     // [E]
    const int*   dst  = (const int*)d_in[4];     // [E]
    const int*   ediv = (const int*)d_in[5];     // [E]
    float* out = (float*)d_out;                  // [N,256]

    const int nNodes = in_sizes[0] / IN_F;
    const int nEdges = in_sizes[3];

    // ws layout
    char* ws = (char*)d_ws;
    const size_t t_bytes      = (size_t)nNodes * OUTC * sizeof(float);   // 102.4 MB
    const size_t wt_bytes     = (size_t)IN_F * OUTC * sizeof(float);     // 128 KB
    const size_t cursor_bytes = (size_t)nNodes * sizeof(int);            // 400 KB
    const size_t pay_bytes    = (size_t)nEdges * sizeof(int);            // 6.4 MB
    const size_t need = t_bytes + wt_bytes + cursor_bytes + pay_bytes;

    float* t = (float*)ws;

    if (ws_size >= need) {
        float* Wt      = (float*)(ws + t_bytes);
        int*   cursor  = (int*)(ws + t_bytes + wt_bytes);
        int*   payload = (int*)(ws + t_bytes + wt_bytes + cursor_bytes);

        hipMemsetAsync(cursor, 0, cursor_bytes, stream);
        transposeW_kernel<<<(IN_F * OUTC) / 256, 256, 0, stream>>>(W, Wt);
        histogram_kernel<<<(nEdges + 255) / 256, 256, 0, stream>>>(dst, cursor, nEdges);
        scan_kernel<<<1, 256, 0, stream>>>(cursor, nNodes);
        place_kernel<<<(nEdges + 255) / 256, 256, 0, stream>>>(src, dst, ediv, cursor,
                                                               payload, nEdges);
        gemm_kernel<<<(nNodes + GM_ROWS - 1) / GM_ROWS, 256, 0, stream>>>(feat, Wt, norm,
                                                                          t, nNodes);
        aggregate_kernel<<<(nNodes + 3) / 4, 256, 0, stream>>>(t, cursor, payload, norm,
                                                               out, nNodes);
    } else {
        // Fallback: round-1 atomic pipeline (needs only t in ws).
        hipMemsetAsync(out, 0, (size_t)nNodes * OUTC * sizeof(float), stream);
        dim3 g1((nNodes + 127) / 128, 2);
        gemm_norm_kernel_fb<<<g1, 256, 0, stream>>>(feat, W, norm, t, nNodes);
        scatter_kernel_fb<<<(nEdges + 3) / 4, 256, 0, stream>>>(t, src, dst, ediv, out,
                                                                nEdges);
        finalize_kernel_fb<<<(nNodes * (OUTC / 4) + 255) / 256, 256, 0, stream>>>(out, norm,
                                                                                  nNodes);
    }
}

// Round 4
// 513.201 us; speedup vs baseline: 1.3984x; 1.3559x over previous
//
#include <hip/hip_runtime.h>

// GeomGCN single-channel:
//   1. Wt[k][c] = W[c][k]                       (transpose, 128x256)
//   2. t[n][c] = (feat[n,:]·Wt[:,c]) * norm[n]  (GEMM, LDS-A / streamed-B)
//   3. counting-sort edges by dst (histogram -> hierarchical scan -> placement)
//   4. per-node wave aggregation (no atomics) + fused *norm + relu
// Constants: N=100000, E=1600000, IN=128, OUT=64, D=4 (D*OUT=256).

#define IN_F   128
#define OUTC   256
#define GM_ROWS 64
#define SCAN_CHUNK 1024   // elements per scan block (256 thr x int4)

// ---------------------------------------------------------------------------
// Wt[k*256 + c] = W[c*128 + k]
// ---------------------------------------------------------------------------
__global__ __launch_bounds__(256) void transposeW_kernel(
    const float* __restrict__ W, float* __restrict__ Wt)
{
    const int idx = blockIdx.x * 256 + threadIdx.x;   // 0..32767
    const int c = idx >> 7;
    const int k = idx & 127;
    Wt[k * OUTC + c] = W[idx];
}

// ---------------------------------------------------------------------------
// GEMM: tile M=64 x N=256(all) x K=128(all). 256 threads, 8x8 microtile.
// ---------------------------------------------------------------------------
__global__ __launch_bounds__(256) void gemm_kernel(
    const float* __restrict__ feat, const float* __restrict__ Wt,
    const float* __restrict__ norm, float* __restrict__ t, int nNodes)
{
    __shared__ float As[128][GM_ROWS + 4];   // [k][m]

    const int tid = threadIdx.x;
    const int m0 = blockIdx.x * GM_ROWS;

    #pragma unroll
    for (int it = 0; it < 8; ++it) {
        const int idx = it * 1024 + tid * 4;
        const int row = idx >> 7;      // 0..63
        const int col = idx & 127;     // k, multiple of 4
        float4 v = make_float4(0.f, 0.f, 0.f, 0.f);
        const int g = m0 + row;
        if (g < nNodes) v = *(const float4*)(feat + (size_t)g * IN_F + col);
        As[col + 0][row] = v.x; As[col + 1][row] = v.y;
        As[col + 2][row] = v.z; As[col + 3][row] = v.w;
    }
    __syncthreads();

    const int tx = tid & 31;          // 32 x 8 = 256 cols
    const int ty = tid >> 5;          // 8 x 8 = 64 rows
    const int mb = ty * 8, nb = tx * 8;
    float acc[8][8] = {};

    #pragma unroll 4
    for (int k = 0; k < 128; ++k) {
        const float4 a0 = *(const float4*)&As[k][mb];
        const float4 a1 = *(const float4*)&As[k][mb + 4];
        const float4 b0 = *(const float4*)(Wt + k * OUTC + nb);
        const float4 b1 = *(const float4*)(Wt + k * OUTC + nb + 4);
        const float a[8] = {a0.x, a0.y, a0.z, a0.w, a1.x, a1.y, a1.z, a1.w};
        const float b[8] = {b0.x, b0.y, b0.z, b0.w, b1.x, b1.y, b1.z, b1.w};
        #pragma unroll
        for (int i = 0; i < 8; ++i)
            #pragma unroll
            for (int j = 0; j < 8; ++j)
                acc[i][j] = fmaf(a[i], b[j], acc[i][j]);
    }

    #pragma unroll
    for (int i = 0; i < 8; ++i) {
        const int gm = m0 + mb + i;
        if (gm >= nNodes) continue;
        const float nm = norm[gm];
        float4 o0, o1;
        o0.x = acc[i][0] * nm; o0.y = acc[i][1] * nm;
        o0.z = acc[i][2] * nm; o0.w = acc[i][3] * nm;
        o1.x = acc[i][4] * nm; o1.y = acc[i][5] * nm;
        o1.z = acc[i][6] * nm; o1.w = acc[i][7] * nm;
        float* p = t + (size_t)gm * OUTC + nb;
        *(float4*)(p + 0) = o0;
        *(float4*)(p + 4) = o1;
    }
}

// ---------------------------------------------------------------------------
// Histogram: cursor[d] += 1 for each edge destination d.
// ---------------------------------------------------------------------------
__global__ __launch_bounds__(256) void histogram_kernel(
    const int* __restrict__ dst, int* __restrict__ cursor, int nEdges)
{
    const int e = blockIdx.x * 256 + threadIdx.x;
    if (e >= nEdges) return;
    atomicAdd(&cursor[dst[e]], 1);
}

// ---------------------------------------------------------------------------
// Hierarchical exclusive scan over cursor[0..n):
//   pass 1: per-block (1024-elem chunk) sums -> bsum[b]
//   pass 2: single block exclusive-scans bsum (<=256 entries)
//   pass 3: per-block local exclusive scan + bsum offset, write back
// ---------------------------------------------------------------------------
__global__ __launch_bounds__(256) void scan_blocksum_kernel(
    const int* __restrict__ c, int* __restrict__ bsum, int n)
{
    const int tid = threadIdx.x;
    const int base = blockIdx.x * SCAN_CHUNK + tid * 4;
    int4 v = make_int4(0, 0, 0, 0);
    if (base + 3 < n)      v = *(const int4*)(c + base);
    else {
        if (base + 0 < n) v.x = c[base + 0];
        if (base + 1 < n) v.y = c[base + 1];
        if (base + 2 < n) v.z = c[base + 2];
    }
    int s = v.x + v.y + v.z + v.w;
    #pragma unroll
    for (int off = 1; off < 64; off <<= 1) s += __shfl_xor(s, off);
    __shared__ int ws[4];
    if ((tid & 63) == 0) ws[tid >> 6] = s;
    __syncthreads();
    if (tid == 0) bsum[blockIdx.x] = ws[0] + ws[1] + ws[2] + ws[3];
}

__global__ __launch_bounds__(256) void scan_bsum_kernel(int* __restrict__ bsum, int nb)
{
    const int tid = threadIdx.x;
    const int lane = tid & 63;
    const int v = (tid < nb) ? bsum[tid] : 0;
    int incl = v;
    #pragma unroll
    for (int off = 1; off < 64; off <<= 1) {
        const int o = __shfl_up(incl, off);
        if (lane >= off) incl += o;
    }
    __shared__ int wsum[4], woff[4];
    if (lane == 63) wsum[tid >> 6] = incl;
    __syncthreads();
    if (tid == 0) { int r = 0; for (int i = 0; i < 4; ++i) { woff[i] = r; r += wsum[i]; } }
    __syncthreads();
    if (tid < nb) bsum[tid] = incl - v + woff[tid >> 6];
}

__global__ __launch_bounds__(256) void scan_final_kernel(
    int* __restrict__ c, const int* __restrict__ bsum, int n)
{
    const int tid = threadIdx.x;
    const int lane = tid & 63;
    const int base = blockIdx.x * SCAN_CHUNK + tid * 4;
    int4 v = make_int4(0, 0, 0, 0);
    if (base + 3 < n)      v = *(const int4*)(c + base);
    else {
        if (base + 0 < n) v.x = c[base + 0];
        if (base + 1 < n) v.y = c[base + 1];
        if (base + 2 < n) v.z = c[base + 2];
    }
    const int s3 = v.x + v.y + v.z + v.w;
    int incl = s3;
    #pragma unroll
    for (int off = 1; off < 64; off <<= 1) {
        const int o = __shfl_up(incl, off);
        if (lane >= off) incl += o;
    }
    __shared__ int wsum[4], woff[4];
    if (lane == 63) wsum[tid >> 6] = incl;
    __syncthreads();
    if (tid == 0) { int r = 0; for (int i = 0; i < 4; ++i) { woff[i] = r; r += wsum[i]; } }
    __syncthreads();
    const int excl = incl - s3 + woff[tid >> 6] + bsum[blockIdx.x];
    int4 o;
    o.x = excl;
    o.y = excl + v.x;
    o.z = excl + v.x + v.y;
    o.w = excl + v.x + v.y + v.z;
    if (base + 3 < n)      *(int4*)(c + base) = o;
    else {
        if (base + 0 < n) c[base + 0] = o.x;
        if (base + 1 < n) c[base + 1] = o.y;
        if (base + 2 < n) c[base + 2] = o.z;
    }
}

// ---------------------------------------------------------------------------
// Placement: pos = cursor[dst]++; payload[pos] = (src<<2)|div.
// After this, cursor[n] == end offset of node n's range.
// ---------------------------------------------------------------------------
__global__ __launch_bounds__(256) void place_kernel(
    const int* __restrict__ src, const int* __restrict__ dst,
    const int* __restrict__ ediv, int* __restrict__ cursor,
    int* __restrict__ payload, int nEdges)
{
    const int e = blockIdx.x * 256 + threadIdx.x;
    if (e >= nEdges) return;
    const int d = dst[e];
    const int pos = atomicAdd(&cursor[d], 1);
    payload[pos] = (src[e] << 2) | ediv[e];
}

// ---------------------------------------------------------------------------
// Aggregation: one wave per node; lane = output feature (0..63), acc per div.
// ---------------------------------------------------------------------------
__global__ __launch_bounds__(256) void aggregate_kernel(
    const float* __restrict__ t, const int* __restrict__ cursor,
    const int* __restrict__ payload, const float* __restrict__ norm,
    float* __restrict__ out, int nNodes)
{
    const int wave = (int)((blockIdx.x * 256u + threadIdx.x) >> 6);
    const int lane = threadIdx.x & 63;
    if (wave >= nNodes) return;
    const int e0 = (wave == 0) ? 0 : cursor[wave - 1];
    const int e1 = cursor[wave];

    float acc0 = 0.f, acc1 = 0.f, acc2 = 0.f, acc3 = 0.f;
    int e = e0;
    for (; e + 1 < e1; e += 2) {
        const int p0 = payload[e];
        const int p1 = payload[e + 1];
        const float v0 = t[(size_t)(p0 >> 2) * OUTC + (p0 & 3) * 64 + lane];
        const float v1 = t[(size_t)(p1 >> 2) * OUTC + (p1 & 3) * 64 + lane];
        const int d0 = p0 & 3, d1 = p1 & 3;
        acc0 += (d0 == 0 ? v0 : 0.f) + (d1 == 0 ? v1 : 0.f);
        acc1 += (d0 == 1 ? v0 : 0.f) + (d1 == 1 ? v1 : 0.f);
        acc2 += (d0 == 2 ? v0 : 0.f) + (d1 == 2 ? v1 : 0.f);
        acc3 += (d0 == 3 ? v0 : 0.f) + (d1 == 3 ? v1 : 0.f);
    }
    if (e < e1) {
        const int p0 = payload[e];
        const float v0 = t[(size_t)(p0 >> 2) * OUTC + (p0 & 3) * 64 + lane];
        const int d0 = p0 & 3;
        acc0 += (d0 == 0 ? v0 : 0.f);
        acc1 += (d0 == 1 ? v0 : 0.f);
        acc2 += (d0 == 2 ? v0 : 0.f);
        acc3 += (d0 == 3 ? v0 : 0.f);
    }

    const float nm = norm[wave];
    float* po = out + (size_t)wave * OUTC;
    po[0 * 64 + lane] = fmaxf(acc0 * nm, 0.f);
    po[1 * 64 + lane] = fmaxf(acc1 * nm, 0.f);
    po[2 * 64 + lane] = fmaxf(acc2 * nm, 0.f);
    po[3 * 64 + lane] = fmaxf(acc3 * nm, 0.f);
}

// ===========================================================================
// Fallback path (atomic pipeline) in case ws_size < required.
// ===========================================================================
__global__ __launch_bounds__(256) void scatter_kernel_fb(
    const float* __restrict__ t, const int* __restrict__ src,
    const int* __restrict__ dst, const int* __restrict__ ediv,
    float* __restrict__ out, int nEdges)
{
    const int wave = (int)((blockIdx.x * 256u + threadIdx.x) >> 6);
    const int lane = threadIdx.x & 63;
    if (wave >= nEdges) return;
    const int c = ediv[wave] * 64 + lane;
    atomicAdd(out + (size_t)dst[wave] * OUTC + c, t[(size_t)src[wave] * OUTC + c]);
}

__global__ __launch_bounds__(256) void finalize_kernel_fb(
    float* __restrict__ out, const float* __restrict__ norm, int nNodes)
{
    const int i = blockIdx.x * 256 + threadIdx.x;
    if (i >= nNodes * (OUTC / 4)) return;
    const float nm = norm[i >> 6];
    float4 v = ((const float4*)out)[i];
    v.x = fmaxf(v.x * nm, 0.f);
    v.y = fmaxf(v.y * nm, 0.f);
    v.z = fmaxf(v.z * nm, 0.f);
    v.w = fmaxf(v.w * nm, 0.f);
    ((float4*)out)[i] = v;
}

// ===========================================================================
extern "C" void kernel_launch(void* const* d_in, const int* in_sizes, int n_in,
                              void* d_out, int out_size, void* d_ws, size_t ws_size,
                              hipStream_t stream) {
    const float* feat = (const float*)d_in[0];   // [N,128]
    const float* W    = (const float*)d_in[1];   // [4,64,128] == [256][128]
    const float* norm = (const float*)d_in[2];   // [N,1]
    const int*   src  = (const int*)d_in[3];     // [E]
    const int*   dst  = (const int*)d_in[4];     // [E]
    const int*   ediv = (const int*)d_in[5];     // [E]
    float* out = (float*)d_out;                  // [N,256]

    const int nNodes = in_sizes[0] / IN_F;
    const int nEdges = in_sizes[3];

    char* ws = (char*)d_ws;
    const size_t t_bytes      = (size_t)nNodes * OUTC * sizeof(float);   // 102.4 MB
    const size_t wt_bytes     = (size_t)IN_F * OUTC * sizeof(float);     // 128 KB
    const size_t cursor_bytes = (size_t)nNodes * sizeof(int);            // 400 KB
    const size_t pay_bytes    = (size_t)nEdges * sizeof(int);            // 6.4 MB
    const size_t bsum_bytes   = 256 * sizeof(int);
    const size_t need = t_bytes + wt_bytes + cursor_bytes + pay_bytes + bsum_bytes;

    float* t = (float*)ws;

    if (ws_size >= need) {
        float* Wt      = (float*)(ws + t_bytes);
        int*   cursor  = (int*)(ws + t_bytes + wt_bytes);
        int*   payload = (int*)(ws + t_bytes + wt_bytes + cursor_bytes);
        int*   bsum    = (int*)(ws + t_bytes + wt_bytes + cursor_bytes + pay_bytes);

        const int nScanBlocks = (nNodes + SCAN_CHUNK - 1) / SCAN_CHUNK;  // 98

        hipMemsetAsync(cursor, 0, cursor_bytes, stream);
        transposeW_kernel<<<(IN_F * OUTC) / 256, 256, 0, stream>>>(W, Wt);
        histogram_kernel<<<(nEdges + 255) / 256, 256, 0, stream>>>(dst, cursor, nEdges);
        scan_blocksum_kernel<<<nScanBlocks, 256, 0, stream>>>(cursor, bsum, nNodes);
        scan_bsum_kernel<<<1, 256, 0, stream>>>(bsum, nScanBlocks);
        scan_final_kernel<<<nScanBlocks, 256, 0, stream>>>(cursor, bsum, nNodes);
        place_kernel<<<(nEdges + 255) / 256, 256, 0, stream>>>(src, dst, ediv, cursor,
                                                               payload, nEdges);
        gemm_kernel<<<(nNodes + GM_ROWS - 1) / GM_ROWS, 256, 0, stream>>>(feat, Wt, norm,
                                                                          t, nNodes);
        aggregate_kernel<<<(nNodes + 3) / 4, 256, 0, stream>>>(t, cursor, payload, norm,
                                                               out, nNodes);
    } else {
        // Fallback: atomic pipeline (needs only t + Wt in ws).
        float* Wt = (float*)(ws + t_bytes);
        hipMemsetAsync(out, 0, (size_t)nNodes * OUTC * sizeof(float), stream);
        transposeW_kernel<<<(IN_F * OUTC) / 256, 256, 0, stream>>>(W, Wt);
        gemm_kernel<<<(nNodes + GM_ROWS - 1) / GM_ROWS, 256, 0, stream>>>(feat, Wt, norm,
                                                                          t, nNodes);
        scatter_kernel_fb<<<(nEdges + 3) / 4, 256, 0, stream>>>(t, src, dst, ediv, out,
                                                                nEdges);
        finalize_kernel_fb<<<(nNodes * (OUTC / 4) + 255) / 256, 256, 0, stream>>>(out, norm,
                                                                                  nNodes);
    }
}

// Round 5
// 399.516 us; speedup vs baseline: 1.7963x; 1.2846x over previous
//
#include <hip/hip_runtime.h>

// GeomGCN single-channel:
//   1. Wt[k][c] = W[c][k]                         (transpose, 128x256)
//   2. t[n][c] = bf16((feat[n,:]·Wt[:,c])*norm[n]) (GEMM, LDS-A / streamed-B)
//   3. two-level counting sort of edges by dst:
//        bucket = dst>>8 (256 nodes/bucket, 391 buckets)
//        A: bucket histogram (LDS-aggregated)        -> bcnt
//        B: 1-block scan                             -> bbase, bfront
//        C: block-local multisplit, run-flushed      -> rec[] (bucket-ordered)
//        D: per-bucket node-level sort in LDS        -> payload[], cursor[]
//   4. per-node wave aggregation (no atomics) + fused *norm + relu
// Constants: N=100000, E=1600000, IN=128, OUT=64, D=4 (D*OUT=256).
// NOTE: assumes nNodes <= 131072 (nBuck <= 512) — true for this problem.

#define IN_F   128
#define OUTC   256
#define GM_ROWS 64
#define EPC    4096    // edges per multisplit chunk (LDS staging)
#define NBMAX  512     // max buckets supported by 1-block scan
#define STGF   5120    // per-bucket fine-sort LDS staging (avg 4096 + 16 sigma)

__device__ inline unsigned short f32_to_bf16(float f) {
    unsigned int u = __float_as_uint(f);
    unsigned int r = (u + 0x7FFFu + ((u >> 16) & 1u)) >> 16;   // RNE
    return (unsigned short)r;
}
__device__ inline float bf16_to_f32(unsigned short h) {
    return __uint_as_float(((unsigned int)h) << 16);
}

// ---------------------------------------------------------------------------
// Wt[k*256 + c] = W[c*128 + k]
// ---------------------------------------------------------------------------
__global__ __launch_bounds__(256) void transposeW_kernel(
    const float* __restrict__ W, float* __restrict__ Wt)
{
    const int idx = blockIdx.x * 256 + threadIdx.x;   // 0..32767
    const int c = idx >> 7;
    const int k = idx & 127;
    Wt[k * OUTC + c] = W[idx];
}

// ---------------------------------------------------------------------------
// GEMM: tile M=64 x N=256(all) x K=128(all). 256 threads, 8x8 microtile.
// Output t is bf16 (halves downstream gather traffic).
// ---------------------------------------------------------------------------
__global__ __launch_bounds__(256) void gemm_kernel(
    const float* __restrict__ feat, const float* __restrict__ Wt,
    const float* __restrict__ norm, unsigned short* __restrict__ t, int nNodes)
{
    __shared__ float As[128][GM_ROWS + 4];   // [k][m]

    const int tid = threadIdx.x;
    const int m0 = blockIdx.x * GM_ROWS;

    #pragma unroll
    for (int it = 0; it < 8; ++it) {
        const int idx = it * 1024 + tid * 4;
        const int row = idx >> 7;      // 0..63
        const int col = idx & 127;     // k, multiple of 4
        float4 v = make_float4(0.f, 0.f, 0.f, 0.f);
        const int g = m0 + row;
        if (g < nNodes) v = *(const float4*)(feat + (size_t)g * IN_F + col);
        As[col + 0][row] = v.x; As[col + 1][row] = v.y;
        As[col + 2][row] = v.z; As[col + 3][row] = v.w;
    }
    __syncthreads();

    const int tx = tid & 31;          // 32 x 8 = 256 cols
    const int ty = tid >> 5;          // 8 x 8 = 64 rows
    const int mb = ty * 8, nb = tx * 8;
    float acc[8][8] = {};

    #pragma unroll 4
    for (int k = 0; k < 128; ++k) {
        const float4 a0 = *(const float4*)&As[k][mb];
        const float4 a1 = *(const float4*)&As[k][mb + 4];
        const float4 b0 = *(const float4*)(Wt + k * OUTC + nb);
        const float4 b1 = *(const float4*)(Wt + k * OUTC + nb + 4);
        const float a[8] = {a0.x, a0.y, a0.z, a0.w, a1.x, a1.y, a1.z, a1.w};
        const float b[8] = {b0.x, b0.y, b0.z, b0.w, b1.x, b1.y, b1.z, b1.w};
        #pragma unroll
        for (int i = 0; i < 8; ++i)
            #pragma unroll
            for (int j = 0; j < 8; ++j)
                acc[i][j] = fmaf(a[i], b[j], acc[i][j]);
    }

    #pragma unroll
    for (int i = 0; i < 8; ++i) {
        const int gm = m0 + mb + i;
        if (gm >= nNodes) continue;
        const float nm = norm[gm];
        union { unsigned short u[8]; uint4 v; } o;
        #pragma unroll
        for (int j = 0; j < 8; ++j) o.u[j] = f32_to_bf16(acc[i][j] * nm);
        *(uint4*)(t + (size_t)gm * OUTC + nb) = o.v;   // 16B aligned
    }
}

// ---------------------------------------------------------------------------
// Pass A: bucket histogram, LDS-aggregated (1 chunk of EPC edges per block).
// ---------------------------------------------------------------------------
__global__ __launch_bounds__(256) void bucket_hist_kernel(
    const int* __restrict__ dst, int* __restrict__ bcnt, int nEdges, int nBuck)
{
    __shared__ int h[NBMAX];
    const int tid = threadIdx.x;
    for (int b = tid; b < nBuck; b += 256) h[b] = 0;
    __syncthreads();
    const int e0 = blockIdx.x * EPC;
    const int cnt = min(EPC, nEdges - e0);
    for (int i = tid; i < cnt; i += 256)
        atomicAdd(&h[((unsigned)dst[e0 + i]) >> 8], 1);
    __syncthreads();
    for (int b = tid; b < nBuck; b += 256)
        if (h[b]) atomicAdd(&bcnt[b], h[b]);
}

// ---------------------------------------------------------------------------
// Pass B: 1-block exclusive scan of bcnt[0..nBuck) -> bbase, bfront (copy).
// Thread t owns elements 2t, 2t+1 (nBuck <= 512).
// ---------------------------------------------------------------------------
__global__ __launch_bounds__(256) void bucket_scan_kernel(
    const int* __restrict__ bcnt, int* __restrict__ bbase,
    int* __restrict__ bfront, int nBuck)
{
    __shared__ int wsum[4], woff[4];
    const int tid = threadIdx.x;
    const int i0 = 2 * tid, i1 = 2 * tid + 1;
    const int h0 = (i0 < nBuck) ? bcnt[i0] : 0;
    const int h1 = (i1 < nBuck) ? bcnt[i1] : 0;
    const int s = h0 + h1;
    int incl = s;
    const int lane = tid & 63;
    #pragma unroll
    for (int off = 1; off < 64; off <<= 1) {
        const int o = __shfl_up(incl, off);
        if (lane >= off) incl += o;
    }
    if (lane == 63) wsum[tid >> 6] = incl;
    __syncthreads();
    if (tid == 0) { int r = 0; for (int i = 0; i < 4; ++i) { woff[i] = r; r += wsum[i]; } }
    __syncthreads();
    const int e = incl - s + woff[tid >> 6];
    if (i0 < nBuck) { bbase[i0] = e;      bfront[i0] = e;      }
    if (i1 < nBuck) { bbase[i1] = e + h0; bfront[i1] = e + h0; }
}

// ---------------------------------------------------------------------------
// Pass C: block-local multisplit. Each block sorts its EPC-edge chunk by
// bucket in LDS, reserves per-bucket global ranges via one atomic per
// (block,bucket), then flushes bucket-ordered runs (coalesced-ish) to rec[].
// rec = {(src<<2)|div, dst}.
// ---------------------------------------------------------------------------
__global__ __launch_bounds__(256) void bucket_place_kernel(
    const int* __restrict__ src, const int* __restrict__ dst,
    const int* __restrict__ ediv, int* __restrict__ bfront,
    uint2* __restrict__ rec, int nEdges, int nBuck)
{
    __shared__ uint2 stg[EPC];                 // 32 KB
    __shared__ unsigned short stgB[EPC];       // 8 KB
    __shared__ int hist[NBMAX], excl[NBMAX], cur[NBMAX], gpos[NBMAX];
    __shared__ int wsum[4], woff[4];

    const int tid = threadIdx.x;
    const int e0 = blockIdx.x * EPC;
    const int cnt = min(EPC, nEdges - e0);

    for (int b = tid; b < nBuck; b += 256) hist[b] = 0;
    __syncthreads();

    for (int i = tid; i < cnt; i += 256)
        atomicAdd(&hist[((unsigned)dst[e0 + i]) >> 8], 1);
    __syncthreads();

    // pair-scan hist -> excl/cur; reserve global ranges -> gpos
    {
        const int i0 = 2 * tid, i1 = 2 * tid + 1;
        const int h0 = (i0 < nBuck) ? hist[i0] : 0;
        const int h1 = (i1 < nBuck) ? hist[i1] : 0;
        const int s = h0 + h1;
        int incl = s;
        const int lane = tid & 63;
        #pragma unroll
        for (int off = 1; off < 64; off <<= 1) {
            const int o = __shfl_up(incl, off);
            if (lane >= off) incl += o;
        }
        if (lane == 63) wsum[tid >> 6] = incl;
        __syncthreads();
        if (tid == 0) { int r = 0; for (int i = 0; i < 4; ++i) { woff[i] = r; r += wsum[i]; } }
        __syncthreads();
        const int e = incl - s + woff[tid >> 6];
        if (i0 < nBuck) { excl[i0] = e;      cur[i0] = e;
                          gpos[i0] = h0 ? atomicAdd(&bfront[i0], h0) : 0; }
        if (i1 < nBuck) { excl[i1] = e + h0; cur[i1] = e + h0;
                          gpos[i1] = h1 ? atomicAdd(&bfront[i1], h1) : 0; }
    }
    __syncthreads();

    for (int i = tid; i < cnt; i += 256) {
        const int e = e0 + i;
        const int d = dst[e];
        const int b = ((unsigned)d) >> 8;
        const int lp = atomicAdd(&cur[b], 1);
        stg[lp]  = make_uint2((unsigned)((src[e] << 2) | ediv[e]), (unsigned)d);
        stgB[lp] = (unsigned short)b;
    }
    __syncthreads();

    for (int s2 = tid; s2 < cnt; s2 += 256) {
        const int b = stgB[s2];
        rec[gpos[b] + (s2 - excl[b])] = stg[s2];
    }
}

// ---------------------------------------------------------------------------
// Pass D: per-bucket node-level counting sort entirely in LDS; streams the
// payload segment out coalesced and writes per-node END cursors.
// ---------------------------------------------------------------------------
__global__ __launch_bounds__(256) void bucket_fine_kernel(
    const uint2* __restrict__ rec, const int* __restrict__ bbase,
    const int* __restrict__ bcnt, int* __restrict__ cursor,
    int* __restrict__ payload, int nNodes)
{
    __shared__ int nhist[256], ncur[256];
    __shared__ int pay[STGF];                  // 20 KB
    __shared__ int wsum[4], woff[4];

    const int tid = threadIdx.x;
    const int b = blockIdx.x;
    const int base = bbase[b];
    const int cnt = bcnt[b];
    const int node0 = b << 8;

    nhist[tid] = 0;
    __syncthreads();
    for (int i = tid; i < cnt; i += 256)
        atomicAdd(&nhist[rec[base + i].y & 255], 1);
    __syncthreads();

    const int v = nhist[tid];
    int incl = v;
    const int lane = tid & 63;
    #pragma unroll
    for (int off = 1; off < 64; off <<= 1) {
        const int o = __shfl_up(incl, off);
        if (lane >= off) incl += o;
    }
    if (lane == 63) wsum[tid >> 6] = incl;
    __syncthreads();
    if (tid == 0) { int r = 0; for (int i = 0; i < 4; ++i) { woff[i] = r; r += wsum[i]; } }
    __syncthreads();
    incl += woff[tid >> 6];
    ncur[tid] = incl - v;                       // exclusive (local)
    if (node0 + tid < nNodes) cursor[node0 + tid] = base + incl;  // END offset
    __syncthreads();

    if (cnt <= STGF) {
        for (int i = tid; i < cnt; i += 256) {
            const uint2 r = rec[base + i];
            pay[atomicAdd(&ncur[r.y & 255], 1)] = (int)r.x;
        }
        __syncthreads();
        for (int i = tid; i < cnt; i += 256) payload[base + i] = pay[i];
    } else {  // overflow safety (statistically never at avg 4096/bucket)
        for (int i = tid; i < cnt; i += 256) {
            const uint2 r = rec[base + i];
            payload[base + atomicAdd(&ncur[r.y & 255], 1)] = (int)r.x;
        }
    }
}

// ---------------------------------------------------------------------------
// Aggregation: one wave per node; lane = output feature (0..63), acc per div.
// t is bf16; accumulate in f32.
// ---------------------------------------------------------------------------
__global__ __launch_bounds__(256) void aggregate_kernel(
    const unsigned short* __restrict__ t, const int* __restrict__ cursor,
    const int* __restrict__ payload, const float* __restrict__ norm,
    float* __restrict__ out, int nNodes)
{
    const int wave = (int)((blockIdx.x * 256u + threadIdx.x) >> 6);
    const int lane = threadIdx.x & 63;
    if (wave >= nNodes) return;
    const int e0 = (wave == 0) ? 0 : cursor[wave - 1];
    const int e1 = cursor[wave];

    float acc0 = 0.f, acc1 = 0.f, acc2 = 0.f, acc3 = 0.f;
    int e = e0;
    for (; e + 1 < e1; e += 2) {
        const int p0 = payload[e];
        const int p1 = payload[e + 1];
        const float v0 = bf16_to_f32(t[(size_t)(p0 >> 2) * OUTC + (p0 & 3) * 64 + lane]);
        const float v1 = bf16_to_f32(t[(size_t)(p1 >> 2) * OUTC + (p1 & 3) * 64 + lane]);
        const int d0 = p0 & 3, d1 = p1 & 3;
        acc0 += (d0 == 0 ? v0 : 0.f) + (d1 == 0 ? v1 : 0.f);
        acc1 += (d0 == 1 ? v0 : 0.f) + (d1 == 1 ? v1 : 0.f);
        acc2 += (d0 == 2 ? v0 : 0.f) + (d1 == 2 ? v1 : 0.f);
        acc3 += (d0 == 3 ? v0 : 0.f) + (d1 == 3 ? v1 : 0.f);
    }
    if (e < e1) {
        const int p0 = payload[e];
        const float v0 = bf16_to_f32(t[(size_t)(p0 >> 2) * OUTC + (p0 & 3) * 64 + lane]);
        const int d0 = p0 & 3;
        acc0 += (d0 == 0 ? v0 : 0.f);
        acc1 += (d0 == 1 ? v0 : 0.f);
        acc2 += (d0 == 2 ? v0 : 0.f);
        acc3 += (d0 == 3 ? v0 : 0.f);
    }

    const float nm = norm[wave];
    float* po = out + (size_t)wave * OUTC;
    po[0 * 64 + lane] = fmaxf(acc0 * nm, 0.f);
    po[1 * 64 + lane] = fmaxf(acc1 * nm, 0.f);
    po[2 * 64 + lane] = fmaxf(acc2 * nm, 0.f);
    po[3 * 64 + lane] = fmaxf(acc3 * nm, 0.f);
}

// ===========================================================================
extern "C" void kernel_launch(void* const* d_in, const int* in_sizes, int n_in,
                              void* d_out, int out_size, void* d_ws, size_t ws_size,
                              hipStream_t stream) {
    const float* feat = (const float*)d_in[0];   // [N,128]
    const float* W    = (const float*)d_in[1];   // [4,64,128] == [256][128]
    const float* norm = (const float*)d_in[2];   // [N,1]
    const int*   src  = (const int*)d_in[3];     // [E]
    const int*   dst  = (const int*)d_in[4];     // [E]
    const int*   ediv = (const int*)d_in[5];     // [E]
    float* out = (float*)d_out;                  // [N,256]

    const int nNodes = in_sizes[0] / IN_F;
    const int nEdges = in_sizes[3];
    const int nBuck  = (nNodes + 255) >> 8;               // 391 (<= NBMAX)
    const int nChunk = (nEdges + EPC - 1) / EPC;          // 391

    // ws layout (all offsets 16B-aligned by construction)
    char* ws = (char*)d_ws;
    const size_t t_bytes      = (size_t)nNodes * OUTC * sizeof(unsigned short); // 51.2 MB
    const size_t rec_bytes    = (size_t)nEdges * sizeof(uint2);                 // 12.8 MB
    const size_t pay_bytes    = (size_t)nEdges * sizeof(int);                   // 6.4 MB
    const size_t cursor_bytes = (size_t)nNodes * sizeof(int);                   // 400 KB
    const size_t wt_bytes     = (size_t)IN_F * OUTC * sizeof(float);            // 128 KB
    const size_t bk_bytes     = (size_t)NBMAX * sizeof(int);

    unsigned short* t  = (unsigned short*)ws;
    uint2* rec     = (uint2*)(ws + t_bytes);
    int*   payload = (int*)(ws + t_bytes + rec_bytes);
    int*   cursor  = (int*)(ws + t_bytes + rec_bytes + pay_bytes);
    float* Wt      = (float*)(ws + t_bytes + rec_bytes + pay_bytes + cursor_bytes);
    int*   bcnt    = (int*)(ws + t_bytes + rec_bytes + pay_bytes + cursor_bytes + wt_bytes);
    int*   bbase   = bcnt + NBMAX;
    int*   bfront  = bcnt + 2 * NBMAX;
    (void)ws_size; (void)out_size; (void)n_in; (void)bk_bytes;

    hipMemsetAsync(bcnt, 0, nBuck * sizeof(int), stream);
    transposeW_kernel<<<(IN_F * OUTC) / 256, 256, 0, stream>>>(W, Wt);
    bucket_hist_kernel<<<nChunk, 256, 0, stream>>>(dst, bcnt, nEdges, nBuck);
    bucket_scan_kernel<<<1, 256, 0, stream>>>(bcnt, bbase, bfront, nBuck);
    bucket_place_kernel<<<nChunk, 256, 0, stream>>>(src, dst, ediv, bfront, rec,
                                                    nEdges, nBuck);
    bucket_fine_kernel<<<nBuck, 256, 0, stream>>>(rec, bbase, bcnt, cursor, payload,
                                                  nNodes);
    gemm_kernel<<<(nNodes + GM_ROWS - 1) / GM_ROWS, 256, 0, stream>>>(feat, Wt, norm,
                                                                      t, nNodes);
    aggregate_kernel<<<(nNodes + 3) / 4, 256, 0, stream>>>(t, cursor, payload, norm,
                                                           out, nNodes);
}

// Round 6
// 371.095 us; speedup vs baseline: 1.9338x; 1.0766x over previous
//
#include <hip/hip_runtime.h>

// GeomGCN single-channel:
//   1. Whi/Wlo = split-bf16 of W [256][128]       (wsplit)
//   2. t[n][c] = bf16((feat[n,:]·W[c,:])*norm[n])  (MFMA GEMM, split-bf16,
//      3 mfma per fragment -> f32-equivalent accuracy)
//   3. two-level counting sort of edges by dst (unchanged from round 5)
//   4. per-node wave aggregation (no atomics) + fused *norm + relu
// Constants: N=100000, E=1600000, IN=128, OUT=64, D=4 (D*OUT=256).

#define IN_F   128
#define OUTC   256
#define EPC    4096
#define NBMAX  512
#define STGF   5120

typedef __bf16 bf16x8 __attribute__((ext_vector_type(8)));
typedef float  f32x4  __attribute__((ext_vector_type(4)));

__device__ inline float bf16_to_f32(unsigned short h) {
    return __uint_as_float(((unsigned int)h) << 16);
}

// ---------------------------------------------------------------------------
// Split W into hi/lo bf16: W ≈ hi + lo, each bf16. 32768 elems.
// ---------------------------------------------------------------------------
__global__ __launch_bounds__(256) void wsplit_kernel(
    const float* __restrict__ W, __bf16* __restrict__ Whi, __bf16* __restrict__ Wlo)
{
    const int idx = blockIdx.x * 256 + threadIdx.x;
    const float v = W[idx];
    const __bf16 h = (__bf16)v;
    Whi[idx] = h;
    Wlo[idx] = (__bf16)(v - (float)h);
}

__device__ inline void split_bf16x8(const float4 q0, const float4 q1,
                                    bf16x8& h, bf16x8& l)
{
    float av[8] = {q0.x, q0.y, q0.z, q0.w, q1.x, q1.y, q1.z, q1.w};
    #pragma unroll
    for (int i = 0; i < 8; ++i) {
        const __bf16 hb = (__bf16)av[i];
        h[i] = hb;
        l[i] = (__bf16)(av[i] - (float)hb);
    }
}

// ---------------------------------------------------------------------------
// MFMA GEMM: one wave computes 32 rows x 256 cols, K=128.
// A/B fragments use a consistent contiguous-k packing (layout-agnostic since
// A and B share the hw k-map); D layout: col=lane&15, row=(lane>>4)*4+reg.
// ---------------------------------------------------------------------------
__global__ __launch_bounds__(256) void gemm_mfma_kernel(
    const float* __restrict__ feat, const __bf16* __restrict__ Whi,
    const __bf16* __restrict__ Wlo, const float* __restrict__ norm,
    __bf16* __restrict__ t, int nNodes)
{
    const int tid  = threadIdx.x;
    const int wave = (blockIdx.x << 2) + (tid >> 6);
    const int lane = tid & 63;
    const int r    = lane & 15;
    const int g    = lane >> 4;
    const int row0 = wave * 32;
    if (row0 >= nNodes) return;

    f32x4 acc[2][16];
    const f32x4 zero = {0.f, 0.f, 0.f, 0.f};
    #pragma unroll
    for (int h = 0; h < 2; ++h)
        #pragma unroll
        for (int c = 0; c < 16; ++c)
            acc[h][c] = zero;

    const int ra0 = row0 + r;
    const int ra1 = row0 + 16 + r;
    const float* pa0 = feat + (size_t)(ra0 < nNodes ? ra0 : 0) * IN_F;
    const float* pa1 = feat + (size_t)(ra1 < nNodes ? ra1 : 0) * IN_F;
    const __bf16* bhp = Whi + r * IN_F;   // B col = c*16 + r
    const __bf16* blp = Wlo + r * IN_F;

    #pragma unroll
    for (int s = 0; s < 4; ++s) {
        const int koff = s * 32 + g * 8;    // 8 contiguous k per lane
        bf16x8 a0h, a0l, a1h, a1l;
        split_bf16x8(*(const float4*)(pa0 + koff), *(const float4*)(pa0 + koff + 4),
                     a0h, a0l);
        split_bf16x8(*(const float4*)(pa1 + koff), *(const float4*)(pa1 + koff + 4),
                     a1h, a1l);
        #pragma unroll
        for (int c = 0; c < 16; ++c) {
            const bf16x8 bh = *(const bf16x8*)(bhp + c * 16 * IN_F + koff);
            const bf16x8 bl = *(const bf16x8*)(blp + c * 16 * IN_F + koff);
            acc[0][c] = __builtin_amdgcn_mfma_f32_16x16x32_bf16(a0h, bh, acc[0][c], 0, 0, 0);
            acc[0][c] = __builtin_amdgcn_mfma_f32_16x16x32_bf16(a0l, bh, acc[0][c], 0, 0, 0);
            acc[0][c] = __builtin_amdgcn_mfma_f32_16x16x32_bf16(a0h, bl, acc[0][c], 0, 0, 0);
            acc[1][c] = __builtin_amdgcn_mfma_f32_16x16x32_bf16(a1h, bh, acc[1][c], 0, 0, 0);
            acc[1][c] = __builtin_amdgcn_mfma_f32_16x16x32_bf16(a1l, bh, acc[1][c], 0, 0, 0);
            acc[1][c] = __builtin_amdgcn_mfma_f32_16x16x32_bf16(a1h, bl, acc[1][c], 0, 0, 0);
        }
    }

    float nv[2][4];
    #pragma unroll
    for (int h = 0; h < 2; ++h)
        #pragma unroll
        for (int j = 0; j < 4; ++j) {
            const int grow = row0 + h * 16 + g * 4 + j;
            nv[h][j] = (grow < nNodes) ? norm[grow] : 0.f;
        }

    #pragma unroll
    for (int h = 0; h < 2; ++h)
        #pragma unroll
        for (int j = 0; j < 4; ++j) {
            const int grow = row0 + h * 16 + g * 4 + j;
            if (grow >= nNodes) continue;
            __bf16* po = t + (size_t)grow * OUTC + r;
            #pragma unroll
            for (int c = 0; c < 16; ++c)
                po[c * 16] = (__bf16)(acc[h][c][j] * nv[h][j]);
        }
}

// ---------------------------------------------------------------------------
// Pass A: bucket histogram, LDS-aggregated.
// ---------------------------------------------------------------------------
__global__ __launch_bounds__(256) void bucket_hist_kernel(
    const int* __restrict__ dst, int* __restrict__ bcnt, int nEdges, int nBuck)
{
    __shared__ int h[NBMAX];
    const int tid = threadIdx.x;
    for (int b = tid; b < nBuck; b += 256) h[b] = 0;
    __syncthreads();
    const int e0 = blockIdx.x * EPC;
    const int cnt = min(EPC, nEdges - e0);
    for (int i = tid; i < cnt; i += 256)
        atomicAdd(&h[((unsigned)dst[e0 + i]) >> 8], 1);
    __syncthreads();
    for (int b = tid; b < nBuck; b += 256)
        if (h[b]) atomicAdd(&bcnt[b], h[b]);
}

// ---------------------------------------------------------------------------
// Pass B: 1-block exclusive scan of bcnt -> bbase, bfront.
// ---------------------------------------------------------------------------
__global__ __launch_bounds__(256) void bucket_scan_kernel(
    const int* __restrict__ bcnt, int* __restrict__ bbase,
    int* __restrict__ bfront, int nBuck)
{
    __shared__ int wsum[4], woff[4];
    const int tid = threadIdx.x;
    const int i0 = 2 * tid, i1 = 2 * tid + 1;
    const int h0 = (i0 < nBuck) ? bcnt[i0] : 0;
    const int h1 = (i1 < nBuck) ? bcnt[i1] : 0;
    const int s = h0 + h1;
    int incl = s;
    const int lane = tid & 63;
    #pragma unroll
    for (int off = 1; off < 64; off <<= 1) {
        const int o = __shfl_up(incl, off);
        if (lane >= off) incl += o;
    }
    if (lane == 63) wsum[tid >> 6] = incl;
    __syncthreads();
    if (tid == 0) { int r = 0; for (int i = 0; i < 4; ++i) { woff[i] = r; r += wsum[i]; } }
    __syncthreads();
    const int e = incl - s + woff[tid >> 6];
    if (i0 < nBuck) { bbase[i0] = e;      bfront[i0] = e;      }
    if (i1 < nBuck) { bbase[i1] = e + h0; bfront[i1] = e + h0; }
}

// ---------------------------------------------------------------------------
// Pass C: block-local multisplit -> bucket-ordered rec[] runs.
// ---------------------------------------------------------------------------
__global__ __launch_bounds__(256) void bucket_place_kernel(
    const int* __restrict__ src, const int* __restrict__ dst,
    const int* __restrict__ ediv, int* __restrict__ bfront,
    uint2* __restrict__ rec, int nEdges, int nBuck)
{
    __shared__ uint2 stg[EPC];
    __shared__ unsigned short stgB[EPC];
    __shared__ int hist[NBMAX], excl[NBMAX], cur[NBMAX], gpos[NBMAX];
    __shared__ int wsum[4], woff[4];

    const int tid = threadIdx.x;
    const int e0 = blockIdx.x * EPC;
    const int cnt = min(EPC, nEdges - e0);

    for (int b = tid; b < nBuck; b += 256) hist[b] = 0;
    __syncthreads();

    for (int i = tid; i < cnt; i += 256)
        atomicAdd(&hist[((unsigned)dst[e0 + i]) >> 8], 1);
    __syncthreads();

    {
        const int i0 = 2 * tid, i1 = 2 * tid + 1;
        const int h0 = (i0 < nBuck) ? hist[i0] : 0;
        const int h1 = (i1 < nBuck) ? hist[i1] : 0;
        const int s = h0 + h1;
        int incl = s;
        const int lane = tid & 63;
        #pragma unroll
        for (int off = 1; off < 64; off <<= 1) {
            const int o = __shfl_up(incl, off);
            if (lane >= off) incl += o;
        }
        if (lane == 63) wsum[tid >> 6] = incl;
        __syncthreads();
        if (tid == 0) { int r = 0; for (int i = 0; i < 4; ++i) { woff[i] = r; r += wsum[i]; } }
        __syncthreads();
        const int e = incl - s + woff[tid >> 6];
        if (i0 < nBuck) { excl[i0] = e;      cur[i0] = e;
                          gpos[i0] = h0 ? atomicAdd(&bfront[i0], h0) : 0; }
        if (i1 < nBuck) { excl[i1] = e + h0; cur[i1] = e + h0;
                          gpos[i1] = h1 ? atomicAdd(&bfront[i1], h1) : 0; }
    }
    __syncthreads();

    for (int i = tid; i < cnt; i += 256) {
        const int e = e0 + i;
        const int d = dst[e];
        const int b = ((unsigned)d) >> 8;
        const int lp = atomicAdd(&cur[b], 1);
        stg[lp]  = make_uint2((unsigned)((src[e] << 2) | ediv[e]), (unsigned)d);
        stgB[lp] = (unsigned short)b;
    }
    __syncthreads();

    for (int s2 = tid; s2 < cnt; s2 += 256) {
        const int b = stgB[s2];
        rec[gpos[b] + (s2 - excl[b])] = stg[s2];
    }
}

// ---------------------------------------------------------------------------
// Pass D: per-bucket node-level counting sort in LDS -> payload[], cursor[].
// ---------------------------------------------------------------------------
__global__ __launch_bounds__(256) void bucket_fine_kernel(
    const uint2* __restrict__ rec, const int* __restrict__ bbase,
    const int* __restrict__ bcnt, int* __restrict__ cursor,
    int* __restrict__ payload, int nNodes)
{
    __shared__ int nhist[256], ncur[256];
    __shared__ int pay[STGF];
    __shared__ int wsum[4], woff[4];

    const int tid = threadIdx.x;
    const int b = blockIdx.x;
    const int base = bbase[b];
    const int cnt = bcnt[b];
    const int node0 = b << 8;

    nhist[tid] = 0;
    __syncthreads();
    for (int i = tid; i < cnt; i += 256)
        atomicAdd(&nhist[rec[base + i].y & 255], 1);
    __syncthreads();

    const int v = nhist[tid];
    int incl = v;
    const int lane = tid & 63;
    #pragma unroll
    for (int off = 1; off < 64; off <<= 1) {
        const int o = __shfl_up(incl, off);
        if (lane >= off) incl += o;
    }
    if (lane == 63) wsum[tid >> 6] = incl;
    __syncthreads();
    if (tid == 0) { int r = 0; for (int i = 0; i < 4; ++i) { woff[i] = r; r += wsum[i]; } }
    __syncthreads();
    incl += woff[tid >> 6];
    ncur[tid] = incl - v;
    if (node0 + tid < nNodes) cursor[node0 + tid] = base + incl;
    __syncthreads();

    if (cnt <= STGF) {
        for (int i = tid; i < cnt; i += 256) {
            const uint2 rr = rec[base + i];
            pay[atomicAdd(&ncur[rr.y & 255], 1)] = (int)rr.x;
        }
        __syncthreads();
        for (int i = tid; i < cnt; i += 256) payload[base + i] = pay[i];
    } else {
        for (int i = tid; i < cnt; i += 256) {
            const uint2 rr = rec[base + i];
            payload[base + atomicAdd(&ncur[rr.y & 255], 1)] = (int)rr.x;
        }
    }
}

// ---------------------------------------------------------------------------
// Aggregation: one wave per node; lane = feature (0..63); acc per div.
// ---------------------------------------------------------------------------
__global__ __launch_bounds__(256) void aggregate_kernel(
    const unsigned short* __restrict__ t, const int* __restrict__ cursor,
    const int* __restrict__ payload, const float* __restrict__ norm,
    float* __restrict__ out, int nNodes)
{
    const int wave = (int)((blockIdx.x * 256u + threadIdx.x) >> 6);
    const int lane = threadIdx.x & 63;
    if (wave >= nNodes) return;
    const int e0 = (wave == 0) ? 0 : cursor[wave - 1];
    const int e1 = cursor[wave];

    float acc0 = 0.f, acc1 = 0.f, acc2 = 0.f, acc3 = 0.f;
    int e = e0;
    for (; e + 3 < e1; e += 4) {
        const int p0 = payload[e + 0];
        const int p1 = payload[e + 1];
        const int p2 = payload[e + 2];
        const int p3 = payload[e + 3];
        const float v0 = bf16_to_f32(t[(size_t)(p0 >> 2) * OUTC + (p0 & 3) * 64 + lane]);
        const float v1 = bf16_to_f32(t[(size_t)(p1 >> 2) * OUTC + (p1 & 3) * 64 + lane]);
        const float v2 = bf16_to_f32(t[(size_t)(p2 >> 2) * OUTC + (p2 & 3) * 64 + lane]);
        const float v3 = bf16_to_f32(t[(size_t)(p3 >> 2) * OUTC + (p3 & 3) * 64 + lane]);
        const int d0 = p0 & 3, d1 = p1 & 3, d2 = p2 & 3, d3 = p3 & 3;
        acc0 += (d0 == 0 ? v0 : 0.f) + (d1 == 0 ? v1 : 0.f) + (d2 == 0 ? v2 : 0.f) + (d3 == 0 ? v3 : 0.f);
        acc1 += (d0 == 1 ? v0 : 0.f) + (d1 == 1 ? v1 : 0.f) + (d2 == 1 ? v2 : 0.f) + (d3 == 1 ? v3 : 0.f);
        acc2 += (d0 == 2 ? v0 : 0.f) + (d1 == 2 ? v1 : 0.f) + (d2 == 2 ? v2 : 0.f) + (d3 == 2 ? v3 : 0.f);
        acc3 += (d0 == 3 ? v0 : 0.f) + (d1 == 3 ? v1 : 0.f) + (d2 == 3 ? v2 : 0.f) + (d3 == 3 ? v3 : 0.f);
    }
    for (; e < e1; ++e) {
        const int p0 = payload[e];
        const float v0 = bf16_to_f32(t[(size_t)(p0 >> 2) * OUTC + (p0 & 3) * 64 + lane]);
        const int d0 = p0 & 3;
        acc0 += (d0 == 0 ? v0 : 0.f);
        acc1 += (d0 == 1 ? v0 : 0.f);
        acc2 += (d0 == 2 ? v0 : 0.f);
        acc3 += (d0 == 3 ? v0 : 0.f);
    }

    const float nm = norm[wave];
    float* po = out + (size_t)wave * OUTC;
    po[0 * 64 + lane] = fmaxf(acc0 * nm, 0.f);
    po[1 * 64 + lane] = fmaxf(acc1 * nm, 0.f);
    po[2 * 64 + lane] = fmaxf(acc2 * nm, 0.f);
    po[3 * 64 + lane] = fmaxf(acc3 * nm, 0.f);
}

// ===========================================================================
extern "C" void kernel_launch(void* const* d_in, const int* in_sizes, int n_in,
                              void* d_out, int out_size, void* d_ws, size_t ws_size,
                              hipStream_t stream) {
    const float* feat = (const float*)d_in[0];   // [N,128]
    const float* W    = (const float*)d_in[1];   // [4,64,128] == [256][128]
    const float* norm = (const float*)d_in[2];   // [N,1]
    const int*   src  = (const int*)d_in[3];     // [E]
    const int*   dst  = (const int*)d_in[4];     // [E]
    const int*   ediv = (const int*)d_in[5];     // [E]
    float* out = (float*)d_out;                  // [N,256]

    const int nNodes = in_sizes[0] / IN_F;
    const int nEdges = in_sizes[3];
    const int nBuck  = (nNodes + 255) >> 8;               // 391
    const int nChunk = (nEdges + EPC - 1) / EPC;          // 391

    char* ws = (char*)d_ws;
    const size_t t_bytes      = (size_t)nNodes * OUTC * sizeof(unsigned short); // 51.2 MB
    const size_t rec_bytes    = (size_t)nEdges * sizeof(uint2);                 // 12.8 MB
    const size_t pay_bytes    = (size_t)nEdges * sizeof(int);                   // 6.4 MB
    const size_t cursor_bytes = (size_t)nNodes * sizeof(int);                   // 400 KB
    const size_t wsp_bytes    = (size_t)IN_F * OUTC * sizeof(__bf16);           // 64 KB each

    __bf16* t      = (__bf16*)ws;
    uint2*  rec    = (uint2*)(ws + t_bytes);
    int*    payload= (int*)(ws + t_bytes + rec_bytes);
    int*    cursor = (int*)(ws + t_bytes + rec_bytes + pay_bytes);
    __bf16* Whi    = (__bf16*)(ws + t_bytes + rec_bytes + pay_bytes + cursor_bytes);
    __bf16* Wlo    = (__bf16*)(ws + t_bytes + rec_bytes + pay_bytes + cursor_bytes + wsp_bytes);
    int*    bcnt   = (int*)(ws + t_bytes + rec_bytes + pay_bytes + cursor_bytes + 2 * wsp_bytes);
    int*    bbase  = bcnt + NBMAX;
    int*    bfront = bcnt + 2 * NBMAX;
    (void)ws_size; (void)out_size; (void)n_in;

    hipMemsetAsync(bcnt, 0, nBuck * sizeof(int), stream);
    wsplit_kernel<<<(IN_F * OUTC) / 256, 256, 0, stream>>>(W, Whi, Wlo);
    bucket_hist_kernel<<<nChunk, 256, 0, stream>>>(dst, bcnt, nEdges, nBuck);
    bucket_scan_kernel<<<1, 256, 0, stream>>>(bcnt, bbase, bfront, nBuck);
    bucket_place_kernel<<<nChunk, 256, 0, stream>>>(src, dst, ediv, bfront, rec,
                                                    nEdges, nBuck);
    bucket_fine_kernel<<<nBuck, 256, 0, stream>>>(rec, bbase, bcnt, cursor, payload,
                                                  nNodes);
    const int gWaves  = (nNodes + 31) / 32;
    const int gBlocks = (gWaves + 3) / 4;
    gemm_mfma_kernel<<<gBlocks, 256, 0, stream>>>(feat, Whi, Wlo, norm, t, nNodes);
    aggregate_kernel<<<(nNodes + 3) / 4, 256, 0, stream>>>((const unsigned short*)t,
                                                           cursor, payload, norm,
                                                           out, nNodes);
}

// Round 7
// 335.798 us; speedup vs baseline: 2.1371x; 1.1051x over previous
//
#include <hip/hip_runtime.h>

// GeomGCN single-channel:
//   1. Bpack = fragment-ordered split-bf16 of W    (wpack, 128 KB)
//   2. t[n][c] = bf16((feat[n,:]·W[c,:])*norm[n])  (MFMA GEMM, B-in-registers,
//      persistent blocks, operand-swapped mfma -> packed row-major stores)
//   3. two-level counting sort of edges by dst (unchanged)
//   4. per-node wave aggregation (no atomics) + fused *norm + relu
// Constants: N=100000, E=1600000, IN=128, OUT=64, D=4 (D*OUT=256).

#define IN_F   128
#define OUTC   256
#define EPC    4096
#define NBMAX  512
#define STGF   5120
#define GEMM_GRID 512

typedef __bf16 bf16x8 __attribute__((ext_vector_type(8)));
typedef float  f32x4  __attribute__((ext_vector_type(4)));

__device__ inline float bf16_to_f32(unsigned short h) {
    return __uint_as_float(((unsigned int)h) << 16);
}

__device__ inline void split_bf16x8(const float4 q0, const float4 q1,
                                    bf16x8& h, bf16x8& l)
{
    float av[8] = {q0.x, q0.y, q0.z, q0.w, q1.x, q1.y, q1.z, q1.w};
    #pragma unroll
    for (int i = 0; i < 8; ++i) {
        const __bf16 hb = (__bf16)av[i];
        h[i] = hb;
        l[i] = (__bf16)(av[i] - (float)hb);
    }
}

// ---------------------------------------------------------------------------
// wpack: W [256][128] f32 -> Bpack fragment-ordered split-bf16.
// Bpack[hi/lo][s][c][lane] : bf16x8 ; frag elem e -> W[(c*16+(lane&15))*128
//                                      + s*32 + (lane>>4)*8 + e]
// hi at [0..4095], lo at [4096..8191]. 4096 threads total.
// ---------------------------------------------------------------------------
__global__ __launch_bounds__(256) void wpack_kernel(
    const float* __restrict__ W, bf16x8* __restrict__ Bpack)
{
    const int idx  = blockIdx.x * 256 + threadIdx.x;   // 0..4095 = (s,c,lane)
    const int lane = idx & 63;
    const int c    = (idx >> 6) & 15;
    const int s    = idx >> 10;
    const int col  = c * 16 + (lane & 15);
    const int k0   = s * 32 + (lane >> 4) * 8;
    const float* p = W + col * IN_F + k0;
    bf16x8 h, l;
    #pragma unroll
    for (int e = 0; e < 8; ++e) {
        const float v = p[e];
        const __bf16 hb = (__bf16)v;
        h[e] = hb;
        l[e] = (__bf16)(v - (float)hb);
    }
    Bpack[idx]        = h;
    Bpack[4096 + idx] = l;
}

// ---------------------------------------------------------------------------
// MFMA GEMM: 512 persistent blocks x 4 waves. Wave w owns cols [w*64, w*64+64);
// its B hi/lo fragments live in 128 VGPRs for the whole kernel. Grid-stride
// over 32-row tiles. mfma(B,A) -> lane holds 4 consecutive cols of one row:
// packed 8B stores, per-lane scalar norm.
// ---------------------------------------------------------------------------
__global__ __launch_bounds__(256, 2) void gemm_mfma_kernel(
    const float* __restrict__ feat, const bf16x8* __restrict__ Bpack,
    const float* __restrict__ norm, __bf16* __restrict__ t,
    int nNodes, int nTiles)
{
    const int tid  = threadIdx.x;
    const int wid  = tid >> 6;
    const int lane = tid & 63;
    const int r    = lane & 15;
    const int g    = lane >> 4;
    const int c0   = wid << 2;          // wave's first c-index (of 16)

    bf16x8 bfh[4][4], bfl[4][4];
    #pragma unroll
    for (int s = 0; s < 4; ++s)
        #pragma unroll
        for (int cc = 0; cc < 4; ++cc) {
            bfh[s][cc] = Bpack[(s * 16 + c0 + cc) * 64 + lane];
            bfl[s][cc] = Bpack[4096 + (s * 16 + c0 + cc) * 64 + lane];
        }

    for (int tile = blockIdx.x; tile < nTiles; tile += gridDim.x) {
        const int row0 = tile * 32;
        const int ra0 = min(row0 + r, nNodes - 1);
        const int ra1 = min(row0 + 16 + r, nNodes - 1);
        const float* pa0 = feat + (size_t)ra0 * IN_F;
        const float* pa1 = feat + (size_t)ra1 * IN_F;

        f32x4 acc[2][4];
        #pragma unroll
        for (int h = 0; h < 2; ++h)
            #pragma unroll
            for (int cc = 0; cc < 4; ++cc)
                acc[h][cc] = (f32x4){0.f, 0.f, 0.f, 0.f};

        #pragma unroll
        for (int s = 0; s < 4; ++s) {
            const int koff = s * 32 + g * 8;
            bf16x8 a0h, a0l, a1h, a1l;
            split_bf16x8(*(const float4*)(pa0 + koff),
                         *(const float4*)(pa0 + koff + 4), a0h, a0l);
            split_bf16x8(*(const float4*)(pa1 + koff),
                         *(const float4*)(pa1 + koff + 4), a1h, a1l);
            #pragma unroll
            for (int cc = 0; cc < 4; ++cc) {
                acc[0][cc] = __builtin_amdgcn_mfma_f32_16x16x32_bf16(bfh[s][cc], a0h, acc[0][cc], 0, 0, 0);
                acc[0][cc] = __builtin_amdgcn_mfma_f32_16x16x32_bf16(bfh[s][cc], a0l, acc[0][cc], 0, 0, 0);
                acc[0][cc] = __builtin_amdgcn_mfma_f32_16x16x32_bf16(bfl[s][cc], a0h, acc[0][cc], 0, 0, 0);
                acc[1][cc] = __builtin_amdgcn_mfma_f32_16x16x32_bf16(bfh[s][cc], a1h, acc[1][cc], 0, 0, 0);
                acc[1][cc] = __builtin_amdgcn_mfma_f32_16x16x32_bf16(bfh[s][cc], a1l, acc[1][cc], 0, 0, 0);
                acc[1][cc] = __builtin_amdgcn_mfma_f32_16x16x32_bf16(bfl[s][cc], a1h, acc[1][cc], 0, 0, 0);
            }
        }

        #pragma unroll
        for (int h = 0; h < 2; ++h) {
            const int grow = row0 + (h << 4) + r;
            if (grow >= nNodes) continue;
            const float nm = norm[grow];
            __bf16* po = t + (size_t)grow * OUTC;
            #pragma unroll
            for (int cc = 0; cc < 4; ++cc) {
                union { __bf16 b[4]; uint2 u; } pk;
                #pragma unroll
                for (int q = 0; q < 4; ++q)
                    pk.b[q] = (__bf16)(acc[h][cc][q] * nm);
                *(uint2*)(po + (c0 + cc) * 16 + (g << 2)) = pk.u;
            }
        }
    }
}

// ---------------------------------------------------------------------------
// Pass A: bucket histogram, LDS-aggregated.
// ---------------------------------------------------------------------------
__global__ __launch_bounds__(256) void bucket_hist_kernel(
    const int* __restrict__ dst, int* __restrict__ bcnt, int nEdges, int nBuck)
{
    __shared__ int h[NBMAX];
    const int tid = threadIdx.x;
    for (int b = tid; b < nBuck; b += 256) h[b] = 0;
    __syncthreads();
    const int e0 = blockIdx.x * EPC;
    const int cnt = min(EPC, nEdges - e0);
    for (int i = tid; i < cnt; i += 256)
        atomicAdd(&h[((unsigned)dst[e0 + i]) >> 8], 1);
    __syncthreads();
    for (int b = tid; b < nBuck; b += 256)
        if (h[b]) atomicAdd(&bcnt[b], h[b]);
}

// ---------------------------------------------------------------------------
// Pass B: 1-block exclusive scan of bcnt -> bbase, bfront.
// ---------------------------------------------------------------------------
__global__ __launch_bounds__(256) void bucket_scan_kernel(
    const int* __restrict__ bcnt, int* __restrict__ bbase,
    int* __restrict__ bfront, int nBuck)
{
    __shared__ int wsum[4], woff[4];
    const int tid = threadIdx.x;
    const int i0 = 2 * tid, i1 = 2 * tid + 1;
    const int h0 = (i0 < nBuck) ? bcnt[i0] : 0;
    const int h1 = (i1 < nBuck) ? bcnt[i1] : 0;
    const int s = h0 + h1;
    int incl = s;
    const int lane = tid & 63;
    #pragma unroll
    for (int off = 1; off < 64; off <<= 1) {
        const int o = __shfl_up(incl, off);
        if (lane >= off) incl += o;
    }
    if (lane == 63) wsum[tid >> 6] = incl;
    __syncthreads();
    if (tid == 0) { int r = 0; for (int i = 0; i < 4; ++i) { woff[i] = r; r += wsum[i]; } }
    __syncthreads();
    const int e = incl - s + woff[tid >> 6];
    if (i0 < nBuck) { bbase[i0] = e;      bfront[i0] = e;      }
    if (i1 < nBuck) { bbase[i1] = e + h0; bfront[i1] = e + h0; }
}

// ---------------------------------------------------------------------------
// Pass C: block-local multisplit -> bucket-ordered rec[] runs.
// ---------------------------------------------------------------------------
__global__ __launch_bounds__(256) void bucket_place_kernel(
    const int* __restrict__ src, const int* __restrict__ dst,
    const int* __restrict__ ediv, int* __restrict__ bfront,
    uint2* __restrict__ rec, int nEdges, int nBuck)
{
    __shared__ uint2 stg[EPC];
    __shared__ unsigned short stgB[EPC];
    __shared__ int hist[NBMAX], excl[NBMAX], cur[NBMAX], gpos[NBMAX];
    __shared__ int wsum[4], woff[4];

    const int tid = threadIdx.x;
    const int e0 = blockIdx.x * EPC;
    const int cnt = min(EPC, nEdges - e0);

    for (int b = tid; b < nBuck; b += 256) hist[b] = 0;
    __syncthreads();

    for (int i = tid; i < cnt; i += 256)
        atomicAdd(&hist[((unsigned)dst[e0 + i]) >> 8], 1);
    __syncthreads();

    {
        const int i0 = 2 * tid, i1 = 2 * tid + 1;
        const int h0 = (i0 < nBuck) ? hist[i0] : 0;
        const int h1 = (i1 < nBuck) ? hist[i1] : 0;
        const int s = h0 + h1;
        int incl = s;
        const int lane = tid & 63;
        #pragma unroll
        for (int off = 1; off < 64; off <<= 1) {
            const int o = __shfl_up(incl, off);
            if (lane >= off) incl += o;
        }
        if (lane == 63) wsum[tid >> 6] = incl;
        __syncthreads();
        if (tid == 0) { int r = 0; for (int i = 0; i < 4; ++i) { woff[i] = r; r += wsum[i]; } }
        __syncthreads();
        const int e = incl - s + woff[tid >> 6];
        if (i0 < nBuck) { excl[i0] = e;      cur[i0] = e;
                          gpos[i0] = h0 ? atomicAdd(&bfront[i0], h0) : 0; }
        if (i1 < nBuck) { excl[i1] = e + h0; cur[i1] = e + h0;
                          gpos[i1] = h1 ? atomicAdd(&bfront[i1], h1) : 0; }
    }
    __syncthreads();

    for (int i = tid; i < cnt; i += 256) {
        const int e = e0 + i;
        const int d = dst[e];
        const int b = ((unsigned)d) >> 8;
        const int lp = atomicAdd(&cur[b], 1);
        stg[lp]  = make_uint2((unsigned)((src[e] << 2) | ediv[e]), (unsigned)d);
        stgB[lp] = (unsigned short)b;
    }
    __syncthreads();

    for (int s2 = tid; s2 < cnt; s2 += 256) {
        const int b = stgB[s2];
        rec[gpos[b] + (s2 - excl[b])] = stg[s2];
    }
}

// ---------------------------------------------------------------------------
// Pass D: per-bucket node-level counting sort in LDS -> payload[], cursor[].
// ---------------------------------------------------------------------------
__global__ __launch_bounds__(256) void bucket_fine_kernel(
    const uint2* __restrict__ rec, const int* __restrict__ bbase,
    const int* __restrict__ bcnt, int* __restrict__ cursor,
    int* __restrict__ payload, int nNodes)
{
    __shared__ int nhist[256], ncur[256];
    __shared__ int pay[STGF];
    __shared__ int wsum[4], woff[4];

    const int tid = threadIdx.x;
    const int b = blockIdx.x;
    const int base = bbase[b];
    const int cnt = bcnt[b];
    const int node0 = b << 8;

    nhist[tid] = 0;
    __syncthreads();
    for (int i = tid; i < cnt; i += 256)
        atomicAdd(&nhist[rec[base + i].y & 255], 1);
    __syncthreads();

    const int v = nhist[tid];
    int incl = v;
    const int lane = tid & 63;
    #pragma unroll
    for (int off = 1; off < 64; off <<= 1) {
        const int o = __shfl_up(incl, off);
        if (lane >= off) incl += o;
    }
    if (lane == 63) wsum[tid >> 6] = incl;
    __syncthreads();
    if (tid == 0) { int r = 0; for (int i = 0; i < 4; ++i) { woff[i] = r; r += wsum[i]; } }
    __syncthreads();
    incl += woff[tid >> 6];
    ncur[tid] = incl - v;
    if (node0 + tid < nNodes) cursor[node0 + tid] = base + incl;
    __syncthreads();

    if (cnt <= STGF) {
        for (int i = tid; i < cnt; i += 256) {
            const uint2 rr = rec[base + i];
            pay[atomicAdd(&ncur[rr.y & 255], 1)] = (int)rr.x;
        }
        __syncthreads();
        for (int i = tid; i < cnt; i += 256) payload[base + i] = pay[i];
    } else {
        for (int i = tid; i < cnt; i += 256) {
            const uint2 rr = rec[base + i];
            payload[base + atomicAdd(&ncur[rr.y & 255], 1)] = (int)rr.x;
        }
    }
}

// ---------------------------------------------------------------------------
// Aggregation: one wave per node; lane = feature (0..63); acc per div.
// ---------------------------------------------------------------------------
__global__ __launch_bounds__(256) void aggregate_kernel(
    const unsigned short* __restrict__ t, const int* __restrict__ cursor,
    const int* __restrict__ payload, const float* __restrict__ norm,
    float* __restrict__ out, int nNodes)
{
    const int wave = (int)((blockIdx.x * 256u + threadIdx.x) >> 6);
    const int lane = threadIdx.x & 63;
    if (wave >= nNodes) return;
    const int e0 = (wave == 0) ? 0 : cursor[wave - 1];
    const int e1 = cursor[wave];

    float acc0 = 0.f, acc1 = 0.f, acc2 = 0.f, acc3 = 0.f;
    int e = e0;
    for (; e + 3 < e1; e += 4) {
        const int p0 = payload[e + 0];
        const int p1 = payload[e + 1];
        const int p2 = payload[e + 2];
        const int p3 = payload[e + 3];
        const float v0 = bf16_to_f32(t[(size_t)(p0 >> 2) * OUTC + (p0 & 3) * 64 + lane]);
        const float v1 = bf16_to_f32(t[(size_t)(p1 >> 2) * OUTC + (p1 & 3) * 64 + lane]);
        const float v2 = bf16_to_f32(t[(size_t)(p2 >> 2) * OUTC + (p2 & 3) * 64 + lane]);
        const float v3 = bf16_to_f32(t[(size_t)(p3 >> 2) * OUTC + (p3 & 3) * 64 + lane]);
        const int d0 = p0 & 3, d1 = p1 & 3, d2 = p2 & 3, d3 = p3 & 3;
        acc0 += (d0 == 0 ? v0 : 0.f) + (d1 == 0 ? v1 : 0.f) + (d2 == 0 ? v2 : 0.f) + (d3 == 0 ? v3 : 0.f);
        acc1 += (d0 == 1 ? v0 : 0.f) + (d1 == 1 ? v1 : 0.f) + (d2 == 1 ? v2 : 0.f) + (d3 == 1 ? v3 : 0.f);
        acc2 += (d0 == 2 ? v0 : 0.f) + (d1 == 2 ? v1 : 0.f) + (d2 == 2 ? v2 : 0.f) + (d3 == 2 ? v3 : 0.f);
        acc3 += (d0 == 3 ? v0 : 0.f) + (d1 == 3 ? v1 : 0.f) + (d2 == 3 ? v2 : 0.f) + (d3 == 3 ? v3 : 0.f);
    }
    for (; e < e1; ++e) {
        const int p0 = payload[e];
        const float v0 = bf16_to_f32(t[(size_t)(p0 >> 2) * OUTC + (p0 & 3) * 64 + lane]);
        const int d0 = p0 & 3;
        acc0 += (d0 == 0 ? v0 : 0.f);
        acc1 += (d0 == 1 ? v0 : 0.f);
        acc2 += (d0 == 2 ? v0 : 0.f);
        acc3 += (d0 == 3 ? v0 : 0.f);
    }

    const float nm = norm[wave];
    float* po = out + (size_t)wave * OUTC;
    po[0 * 64 + lane] = fmaxf(acc0 * nm, 0.f);
    po[1 * 64 + lane] = fmaxf(acc1 * nm, 0.f);
    po[2 * 64 + lane] = fmaxf(acc2 * nm, 0.f);
    po[3 * 64 + lane] = fmaxf(acc3 * nm, 0.f);
}

// ===========================================================================
extern "C" void kernel_launch(void* const* d_in, const int* in_sizes, int n_in,
                              void* d_out, int out_size, void* d_ws, size_t ws_size,
                              hipStream_t stream) {
    const float* feat = (const float*)d_in[0];   // [N,128]
    const float* W    = (const float*)d_in[1];   // [4,64,128] == [256][128]
    const float* norm = (const float*)d_in[2];   // [N,1]
    const int*   src  = (const int*)d_in[3];     // [E]
    const int*   dst  = (const int*)d_in[4];     // [E]
    const int*   ediv = (const int*)d_in[5];     // [E]
    float* out = (float*)d_out;                  // [N,256]

    const int nNodes = in_sizes[0] / IN_F;
    const int nEdges = in_sizes[3];
    const int nBuck  = (nNodes + 255) >> 8;               // 391
    const int nChunk = (nEdges + EPC - 1) / EPC;          // 391
    const int nTiles = (nNodes + 31) / 32;                // 3125

    char* ws = (char*)d_ws;
    const size_t t_bytes      = (size_t)nNodes * OUTC * sizeof(unsigned short); // 51.2 MB
    const size_t rec_bytes    = (size_t)nEdges * sizeof(uint2);                 // 12.8 MB
    const size_t pay_bytes    = (size_t)nEdges * sizeof(int);                   // 6.4 MB
    const size_t cursor_bytes = (size_t)nNodes * sizeof(int);                   // 400 KB
    const size_t bp_bytes     = 8192 * sizeof(bf16x8);                          // 128 KB

    __bf16* t      = (__bf16*)ws;
    uint2*  rec    = (uint2*)(ws + t_bytes);
    int*    payload= (int*)(ws + t_bytes + rec_bytes);
    int*    cursor = (int*)(ws + t_bytes + rec_bytes + pay_bytes);
    bf16x8* Bpack  = (bf16x8*)(ws + t_bytes + rec_bytes + pay_bytes + cursor_bytes);
    int*    bcnt   = (int*)(ws + t_bytes + rec_bytes + pay_bytes + cursor_bytes + bp_bytes);
    int*    bbase  = bcnt + NBMAX;
    int*    bfront = bcnt + 2 * NBMAX;
    (void)ws_size; (void)out_size; (void)n_in;

    hipMemsetAsync(bcnt, 0, nBuck * sizeof(int), stream);
    wpack_kernel<<<16, 256, 0, stream>>>(W, Bpack);
    bucket_hist_kernel<<<nChunk, 256, 0, stream>>>(dst, bcnt, nEdges, nBuck);
    bucket_scan_kernel<<<1, 256, 0, stream>>>(bcnt, bbase, bfront, nBuck);
    bucket_place_kernel<<<nChunk, 256, 0, stream>>>(src, dst, ediv, bfront, rec,
                                                    nEdges, nBuck);
    bucket_fine_kernel<<<nBuck, 256, 0, stream>>>(rec, bbase, bcnt, cursor, payload,
                                                  nNodes);
    gemm_mfma_kernel<<<GEMM_GRID, 256, 0, stream>>>(feat, Bpack, norm, t,
                                                    nNodes, nTiles);
    aggregate_kernel<<<(nNodes + 3) / 4, 256, 0, stream>>>((const unsigned short*)t,
                                                           cursor, payload, norm,
                                                           out, nNodes);
}